// Round 7
// baseline (673.521 us; speedup 1.0000x reference)
//
#include <hip/hip_runtime.h>
#include <hip/hip_fp16.h>

#define N_PTS   100000
#define KNB     16
#define CIN     128
#define COUT    256
#define NKP     15
#define CCH     131
#define KP      2112         // 132 channel slots * 16 m-slots, c-major (m fastest)
#define MPAD    100096       // 782 * 128
#define CHROWS  16384        // 66 MB agg chunk; gemm grid (2,128)=256 blocks

typedef _Float16 f16x8 __attribute__((ext_vector_type(8)));
typedef float    f32x4 __attribute__((ext_vector_type(4)));
typedef unsigned int u32x2 __attribute__((ext_vector_type(2)));

__device__ __forceinline__ void g2lds16(const void* g, void* l) {
  __builtin_amdgcn_global_load_lds((const __attribute__((address_space(1))) void*)g,
                                   (__attribute__((address_space(3))) void*)l, 16, 0, 0);
}

// ---------------- prep: x -> f16 ----------------
__global__ __launch_bounds__(256) void k_prep_x(const float* __restrict__ x,
                                                __half* __restrict__ xh) {
  int i = blockIdx.x * 256 + threadIdx.x;           // 3.2M threads, 4 elems each
  float4 v = ((const float4*)x)[i];
  __half2* o = (__half2*)xh;
  o[i * 2]     = __floats2half2_rn(v.x, v.y);
  o[i * 2 + 1] = __floats2half2_rn(v.z, v.w);
}

// ---------------- prep: W repack + BN fold ----------------
// wt[o][c*16+m]: c<128 -> conv_w[o][c+3][m] (x-part), c=128..130 -> conv_w[o][c-128][m] (pj)
__global__ __launch_bounds__(256) void k_prep_w(
    const float* __restrict__ w, const float* __restrict__ cb,
    const float* __restrict__ g, const float* __restrict__ be,
    const float* __restrict__ mu, const float* __restrict__ var,
    __half* __restrict__ wt, float* __restrict__ sc, float* __restrict__ sh) {
  int gid = blockIdx.x * 256 + threadIdx.x;         // COUT*KP threads
  int o = gid / KP, r = gid - o * KP;
  int c = r >> 4, m = r & 15;
  float v = 0.f;
  if (m < 15 && c < 131) {
    int refch = (c < 128) ? (c + 3) : (c - 128);
    v = w[(o * CCH + refch) * NKP + m];
  }
  wt[gid] = __float2half(v);
  if (gid < COUT) {
    float s = g[gid] / sqrtf(var[gid] + 1e-5f);
    sc[gid] = s;
    sh[gid] = (cb[gid] - mu[gid]) * s + be[gid];
  }
}

// ---------------- agg: direct-gather MFMA aggregation, one wave per point ----------------
// agg row (c-major): col = c*16 + m. Per channel-group g (16 ch):
//   A[m=l&15][k=(l>>4)*8+i] = corr (lanes<32; 0 elsewhere kills k>=16 garbage),
//   B[k][cfix=l&15] = xh[nbr_k][g*16+cfix],
//   D: lane holds cols (g*16+cfix)*16 + g4 + 0..3  -> dense 512B span per wave-store.
__global__ __launch_bounds__(256) void k_agg(
    const float* __restrict__ p, const __half* __restrict__ xh,
    const float* __restrict__ kp, const int* __restrict__ idx,
    __half* __restrict__ agg, int r0) {
  __shared__ float pj[4][16][4];
  __shared__ float co[4][16][16];                   // co[k][m]
  const int l = threadIdx.x & 63;
  const int w = threadIdx.x >> 6;
  const int n = r0 + blockIdx.x * 4 + w;
  const int nc = (n < N_PTS) ? n : (N_PTS - 1);
  const int nbr = idx[nc * KNB + (l & 15)];

  // phase 0: relative coords + max-norm (replicated per 16-lane group)
  const float cx = p[nc * 3], cy = p[nc * 3 + 1], cz = p[nc * 3 + 2];
  float ax = p[nbr * 3]     - cx;
  float ay = p[nbr * 3 + 1] - cy;
  float az = p[nbr * 3 + 2] - cz;
  float mx = sqrtf(ax * ax + ay * ay + az * az);
  #pragma unroll
  for (int d = 1; d < 16; d <<= 1) mx = fmaxf(mx, __shfl_xor(mx, d));
  const float inv = 1.0f / (mx + 1e-10f);
  ax *= inv; ay *= inv; az *= inv;

  // neighbor-row byte offsets for this lane's k-set: k = ((l>>4)&1)*8 + i
  int rowoff[8];
  #pragma unroll
  for (int i = 0; i < 8; i++)
    rowoff[i] = __shfl(nbr, ((l >> 4) & 1) * 8 + i) * (CIN * 2);

  if (l < 16) { pj[w][l][0] = ax; pj[w][l][1] = ay; pj[w][l][2] = az; pj[w][l][3] = 0.f; }
  __syncthreads();

  // phase 1: corr for k=l>>2, m=(l&3)*4+j  (m==15 -> 0)
  const int k1 = l >> 2;
  f32x4 pv = *(const f32x4*)&pj[w][k1][0];
  f32x4 cc;
  #pragma unroll
  for (int j = 0; j < 4; j++) {
    int m = (l & 3) * 4 + j;
    if (m < 15) {
      float dx = kp[m * 3] - pv[0], dy = kp[m * 3 + 1] - pv[1], dz = kp[m * 3 + 2] - pv[2];
      cc[j] = __expf((dx * dx + dy * dy + dz * dz) * -5.5555553f);
    } else cc[j] = 0.f;
  }
  *(f32x4*)&co[w][k1][(l & 3) * 4] = cc;
  __syncthreads();

  const int cfix = l & 15;
  const int g4 = (l >> 4) * 4;

  // hoisted gather: ALL 64 x-loads in flight before any MFMA (latency paid once).
  // Lanes 32-63 load duplicate (valid, finite) rows; af==0 there annihilates them.
  const char* xb = (const char*)xh + cfix * 2;
  unsigned short xv[8][8];
  #pragma unroll
  for (int g = 0; g < 8; g++)
    #pragma unroll
    for (int i = 0; i < 8; i++)
      xv[g][i] = *(const unsigned short*)(xb + (size_t)(unsigned)rowoff[i] + g * 32);

  // A-frag: corr[m=l&15][k=(l>>4)*8+i], lanes 0..31; zero elsewhere
  f16x8 af = {};
  if (l < 32) {
    #pragma unroll
    for (int i = 0; i < 8; i++)
      af[i] = (_Float16)co[w][(l >> 4) * 8 + i][l & 15];
  }

  const bool live = (n < N_PTS);
  char* outp = (char*)(agg + (size_t)(n - r0) * KP) + cfix * 32 + g4 * 2;

  #pragma unroll
  for (int g = 0; g < 8; g++) {
    f16x8 bf;
    #pragma unroll
    for (int i = 0; i < 8; i++)
      bf[i] = *(_Float16*)&xv[g][i];
    f32x4 d = __builtin_amdgcn_mfma_f32_16x16x32_f16(af, bf, (f32x4){0.f, 0.f, 0.f, 0.f}, 0, 0, 0);
    if (live) {
      __half2 h0 = __floats2half2_rn(d[0], d[1]);
      __half2 h1 = __floats2half2_rn(d[2], d[3]);
      u32x2 u; u.x = *(unsigned int*)&h0; u.y = *(unsigned int*)&h1;
      *(u32x2*)(outp + g * 512) = u;
    }
  }
  // group 8: pj channels (c=128..130) + zero col c=131
  {
    f16x8 bf = {};
    if (l < 32 && cfix < 3) {
      #pragma unroll
      for (int i = 0; i < 8; i++)
        bf[i] = (_Float16)pj[w][(l >> 4) * 8 + i][cfix];
    }
    f32x4 d = __builtin_amdgcn_mfma_f32_16x16x32_f16(af, bf, (f32x4){0.f, 0.f, 0.f, 0.f}, 0, 0, 0);
    if (live && cfix < 4) {
      __half2 h0 = __floats2half2_rn(d[0], d[1]);
      __half2 h1 = __floats2half2_rn(d[2], d[3]);
      u32x2 u; u.x = *(unsigned int*)&h0; u.y = *(unsigned int*)&h1;
      *(u32x2*)(outp + 8 * 512) = u;
    }
  }
}

// ---------------- GEMM (single-buffer m97 structure): [rows,KP] x [COUT,KP]^T + BN + ReLU ----
__global__ __launch_bounds__(256) void k_gemm(
    const __half* __restrict__ A, const __half* __restrict__ B,
    const float* __restrict__ sc, const float* __restrict__ sh,
    float* __restrict__ out, int r0) {
  __shared__ __align__(16) __half Al[128 * 64];
  __shared__ __align__(16) __half Bl[128 * 64];
  const int t = threadIdx.x;
  const int l = t & 63;
  const int bn = blockIdx.x, bm = blockIdx.y;
  const int m0 = bm * 128, n0 = bn * 128;
  const int w = t >> 6;
  const int wm = w >> 1, wn = w & 1;

  f32x4 acc[4][4] = {};

  const int arow = t >> 3;
  const int kb   = (t & 7) << 4;
  const int kbsw = kb ^ ((arow & 7) << 4);
  const char* aSrc = (const char*)(A + (size_t)(m0 + arow) * KP) + kbsw;
  const char* bSrc = (const char*)(B + (size_t)(n0 + arow) * KP) + kbsw;
  char* aDst = (char*)Al + t * 16;
  char* bDst = (char*)Bl + t * 16;
  const size_t rowStride32 = (size_t)32 * KP * 2;

  for (int kt = 0; kt < KP / 64; kt++) {
    __syncthreads();
    #pragma unroll
    for (int i = 0; i < 4; i++) {
      g2lds16(aSrc + i * rowStride32 + (size_t)kt * 128, aDst + i * 4096);
      g2lds16(bSrc + i * rowStride32 + (size_t)kt * 128, bDst + i * 4096);
    }
    __syncthreads();
    #pragma unroll
    for (int kk = 0; kk < 2; kk++) {
      f16x8 af[4], bf[4];
      const int rbyte = ((l >> 4) << 4) + kk * 64;
      #pragma unroll
      for (int i = 0; i < 4; i++) {
        const int ra = wm * 64 + i * 16 + (l & 15);
        af[i] = *(const f16x8*)((const char*)Al + ra * 128 + (rbyte ^ ((ra & 7) << 4)));
        const int rb = wn * 64 + i * 16 + (l & 15);
        bf[i] = *(const f16x8*)((const char*)Bl + rb * 128 + (rbyte ^ ((rb & 7) << 4)));
      }
      #pragma unroll
      for (int i = 0; i < 4; i++)
        #pragma unroll
        for (int j = 0; j < 4; j++)
          acc[i][j] = __builtin_amdgcn_mfma_f32_16x16x32_f16(af[i], bf[j], acc[i][j], 0, 0, 0);
    }
  }

  #pragma unroll
  for (int j = 0; j < 4; j++) {
    const int col = n0 + wn * 64 + j * 16 + (l & 15);
    const float s = sc[col], h = sh[col];
    #pragma unroll
    for (int i = 0; i < 4; i++) {
      const int rr = r0 + m0 + wm * 64 + i * 16 + ((l >> 4) << 2);
      #pragma unroll
      for (int rg = 0; rg < 4; rg++) {
        const int r = rr + rg;
        if (r < N_PTS) {
          float v = acc[i][j][rg] * s + h;
          out[(size_t)r * COUT + col] = fmaxf(v, 0.f);
        }
      }
    }
  }
}

extern "C" void kernel_launch(void* const* d_in, const int* in_sizes, int n_in,
                              void* d_out, int out_size, void* d_ws, size_t ws_size,
                              hipStream_t stream) {
  (void)in_sizes; (void)n_in; (void)out_size;
  const float* p   = (const float*)d_in[0];
  const float* x   = (const float*)d_in[1];
  const float* kp  = (const float*)d_in[2];
  const float* w   = (const float*)d_in[3];
  const float* cb  = (const float*)d_in[4];
  const float* g   = (const float*)d_in[5];
  const float* be  = (const float*)d_in[6];
  const float* mu  = (const float*)d_in[7];
  const float* var = (const float*)d_in[8];
  const int* idx   = (const int*)d_in[9];
  float* out = (float*)d_out;

  char* ws = (char*)d_ws;
  size_t off = 0;
  __half* wt  = (__half*)(ws + off); off += (size_t)COUT * KP * 2;   // 1.1 MB
  float*  sc  = (float*)(ws + off);  off += 1024;
  float*  sh  = (float*)(ws + off);  off += 1024;
  __half* xh  = (__half*)(ws + off); off += (size_t)N_PTS * CIN * 2; // 25.6 MB
  __half* agg = (__half*)(ws + off);
  size_t avail = (ws_size > off) ? (ws_size - off) : 0;

  size_t maxrows = avail / ((size_t)KP * 2);
  int rows = CHROWS;                                  // L3-resident chunk
  if (maxrows < (size_t)rows) rows = (int)(maxrows & ~(size_t)127);
  if (rows < 128) rows = 128;

  hipLaunchKernelGGL(k_prep_x, dim3(N_PTS * CIN / 1024), dim3(256), 0, stream, x, xh);
  hipLaunchKernelGGL(k_prep_w, dim3(COUT * KP / 256), dim3(256), 0, stream,
                     w, cb, g, be, mu, var, wt, sc, sh);

  for (int row0 = 0; row0 < N_PTS; row0 += rows) {
    int rr = MPAD - row0;
    if (rr > rows) rr = rows;
    hipLaunchKernelGGL(k_agg, dim3(rr / 4), dim3(256), 0, stream, p, xh, kp, idx, agg, row0);
    hipLaunchKernelGGL(k_gemm, dim3(2, rr / 128), dim3(256), 0, stream, agg, wt, sc, sh, out, row0);
  }
}

// Round 8
// 556.891 us; speedup vs baseline: 1.2094x; 1.2094x over previous
//
#include <hip/hip_runtime.h>
#include <hip/hip_fp16.h>

#define N_PTS   100000
#define KNB     16
#define CIN     128
#define COUT    256
#define NKP     15
#define CCH     131
#define KP      2112         // 132 c-slots * 16 m-slots, c-major (m fastest)
#define MPAD    100096       // 782 * 128
#define CHROWS  50048        // 2 chunks; agg buffer 211 MB (ws = 400 MB total)

typedef _Float16 f16x8 __attribute__((ext_vector_type(8)));
typedef float    f32x4 __attribute__((ext_vector_type(4)));
typedef unsigned int u32x2 __attribute__((ext_vector_type(2)));

__device__ __forceinline__ void g2lds16(const void* g, void* l) {
  __builtin_amdgcn_global_load_lds((const __attribute__((address_space(1))) void*)g,
                                   (__attribute__((address_space(3))) void*)l, 16, 0, 0);
}

// ---------------- prep: x -> f16 ----------------
__global__ __launch_bounds__(256) void k_prep_x(const float* __restrict__ x,
                                                __half* __restrict__ xh) {
  int i = blockIdx.x * 256 + threadIdx.x;           // 3.2M threads, 4 elems each
  float4 v = ((const float4*)x)[i];
  __half2* o = (__half2*)xh;
  o[i * 2]     = __floats2half2_rn(v.x, v.y);
  o[i * 2 + 1] = __floats2half2_rn(v.z, v.w);
}

// ---------------- prep: W repack + BN fold ----------------
// c-slot -> channel permutation: c = g*16+j (c<128) maps to x-channel 8j+g
// (so k_agg's lane-j 16B load [8j..8j+8) supplies slot (g,j) from half g).
// c in 128..130 -> pj channel c-128. Reference channel order: [pj(3), x(128)].
__global__ __launch_bounds__(256) void k_prep_w(
    const float* __restrict__ w, const float* __restrict__ cb,
    const float* __restrict__ g, const float* __restrict__ be,
    const float* __restrict__ mu, const float* __restrict__ var,
    __half* __restrict__ wt, float* __restrict__ sc, float* __restrict__ sh) {
  int gid = blockIdx.x * 256 + threadIdx.x;         // COUT*KP threads
  int o = gid / KP, r = gid - o * KP;
  int c = r >> 4, m = r & 15;
  float v = 0.f;
  if (m < 15 && c < 131) {
    int refch = (c < 128) ? (8 * (c & 15) + (c >> 4) + 3) : (c - 128);
    v = w[(o * CCH + refch) * NKP + m];
  }
  wt[gid] = __float2half(v);
  if (gid < COUT) {
    float s = g[gid] / sqrtf(var[gid] + 1e-5f);
    sc[gid] = s;
    sh[gid] = (cb[gid] - mu[gid]) * s + be[gid];
  }
}

// ---------------- agg: direct-gather MFMA aggregation, one wave per point ----------------
// Per group g: A[m=l&15][k=(l>>4)*8+i] = corr (lanes<32), B[k][j=l&15] = xq[i][g]
// (= channel 8j+g of neighbor k). D lane holds cols (g*16+j)*16 + g4+0..3 ->
// dense 512B store span per wave per group.
__global__ __launch_bounds__(256) void k_agg(
    const float* __restrict__ p, const __half* __restrict__ xh,
    const float* __restrict__ kp, const int* __restrict__ idx,
    __half* __restrict__ agg, int r0) {
  __shared__ float pj[4][16][4];
  __shared__ float co[4][16][16];                   // co[k][m]
  const int l = threadIdx.x & 63;
  const int w = threadIdx.x >> 6;
  const int n = r0 + blockIdx.x * 4 + w;
  const int nc = (n < N_PTS) ? n : (N_PTS - 1);
  const int cfix = l & 15;
  const int nbr = idx[nc * KNB + cfix];

  // neighbor-row byte offsets for this lane's k-set: k = ((l>>4)&1)*8 + i
  int rowoff[8];
  #pragma unroll
  for (int i = 0; i < 8; i++)
    rowoff[i] = __shfl(nbr, ((l >> 4) & 1) * 8 + i) * (CIN * 2);

  // hoisted gather: 8 x 16B per lane; 16 lanes cover 256B contiguous per row.
  // Lanes 32-63 duplicate lanes 0-31 (valid addrs; af==0 annihilates them).
  const char* xb = (const char*)xh + cfix * 16;
  f16x8 xq[8];
  #pragma unroll
  for (int i = 0; i < 8; i++)
    xq[i] = *(const f16x8*)(xb + (size_t)(unsigned)rowoff[i]);

  // phase 0: relative coords + max-norm (replicated per 16-lane group)
  const float cx = p[nc * 3], cy = p[nc * 3 + 1], cz = p[nc * 3 + 2];
  float ax = p[nbr * 3]     - cx;
  float ay = p[nbr * 3 + 1] - cy;
  float az = p[nbr * 3 + 2] - cz;
  float mx = sqrtf(ax * ax + ay * ay + az * az);
  #pragma unroll
  for (int d = 1; d < 16; d <<= 1) mx = fmaxf(mx, __shfl_xor(mx, d));
  const float inv = 1.0f / (mx + 1e-10f);
  ax *= inv; ay *= inv; az *= inv;

  if (l < 16) { pj[w][l][0] = ax; pj[w][l][1] = ay; pj[w][l][2] = az; pj[w][l][3] = 0.f; }
  __syncthreads();

  // phase 1: corr for k=l>>2, m=(l&3)*4+j  (m==15 -> 0)
  const int k1 = l >> 2;
  f32x4 pv = *(const f32x4*)&pj[w][k1][0];
  f32x4 cc;
  #pragma unroll
  for (int j = 0; j < 4; j++) {
    int m = (l & 3) * 4 + j;
    if (m < 15) {
      float dx = kp[m * 3] - pv[0], dy = kp[m * 3 + 1] - pv[1], dz = kp[m * 3 + 2] - pv[2];
      cc[j] = __expf((dx * dx + dy * dy + dz * dz) * -5.5555553f);
    } else cc[j] = 0.f;
  }
  *(f32x4*)&co[w][k1][(l & 3) * 4] = cc;
  __syncthreads();

  // A-frag: corr[m=l&15][k=(l>>4)*8+i], lanes 0..31; zero elsewhere
  f16x8 af = {};
  if (l < 32) {
    #pragma unroll
    for (int i = 0; i < 8; i++)
      af[i] = (_Float16)co[w][(l >> 4) * 8 + i][l & 15];
  }

  const bool live = (n < N_PTS);
  const int g4 = (l >> 4) * 4;
  char* outp = (char*)(agg + (size_t)(n - r0) * KP) + cfix * 32 + g4 * 2;

  #pragma unroll
  for (int g = 0; g < 8; g++) {
    f16x8 bf;
    #pragma unroll
    for (int i = 0; i < 8; i++)
      bf[i] = xq[i][g];
    f32x4 d = __builtin_amdgcn_mfma_f32_16x16x32_f16(af, bf, (f32x4){0.f, 0.f, 0.f, 0.f}, 0, 0, 0);
    if (live) {
      __half2 h0 = __floats2half2_rn(d[0], d[1]);
      __half2 h1 = __floats2half2_rn(d[2], d[3]);
      u32x2 u; u.x = *(unsigned int*)&h0; u.y = *(unsigned int*)&h1;
      *(u32x2*)(outp + g * 512) = u;
    }
  }
  // group 8: pj channels (c=128..130) + zero col c=131
  {
    f16x8 bf = {};
    if (l < 32 && cfix < 3) {
      #pragma unroll
      for (int i = 0; i < 8; i++)
        bf[i] = (_Float16)pj[w][(l >> 4) * 8 + i][cfix];
    }
    f32x4 d = __builtin_amdgcn_mfma_f32_16x16x32_f16(af, bf, (f32x4){0.f, 0.f, 0.f, 0.f}, 0, 0, 0);
    if (live && cfix < 4) {
      __half2 h0 = __floats2half2_rn(d[0], d[1]);
      __half2 h1 = __floats2half2_rn(d[2], d[3]);
      u32x2 u; u.x = *(unsigned int*)&h0; u.y = *(unsigned int*)&h1;
      *(u32x2*)(outp + 8 * 512) = u;
    }
  }
}

// ---------------- GEMM (single-buffer m97 structure): [rows,KP] x [COUT,KP]^T + BN + ReLU ----
__global__ __launch_bounds__(256) void k_gemm(
    const __half* __restrict__ A, const __half* __restrict__ B,
    const float* __restrict__ sc, const float* __restrict__ sh,
    float* __restrict__ out, int r0) {
  __shared__ __align__(16) __half Al[128 * 64];
  __shared__ __align__(16) __half Bl[128 * 64];
  const int t = threadIdx.x;
  const int l = t & 63;
  const int bn = blockIdx.x, bm = blockIdx.y;
  const int m0 = bm * 128, n0 = bn * 128;
  const int w = t >> 6;
  const int wm = w >> 1, wn = w & 1;

  f32x4 acc[4][4] = {};

  const int arow = t >> 3;
  const int kb   = (t & 7) << 4;
  const int kbsw = kb ^ ((arow & 7) << 4);
  const char* aSrc = (const char*)(A + (size_t)(m0 + arow) * KP) + kbsw;
  const char* bSrc = (const char*)(B + (size_t)(n0 + arow) * KP) + kbsw;
  char* aDst = (char*)Al + t * 16;
  char* bDst = (char*)Bl + t * 16;
  const size_t rowStride32 = (size_t)32 * KP * 2;

  for (int kt = 0; kt < KP / 64; kt++) {
    __syncthreads();
    #pragma unroll
    for (int i = 0; i < 4; i++) {
      g2lds16(aSrc + i * rowStride32 + (size_t)kt * 128, aDst + i * 4096);
      g2lds16(bSrc + i * rowStride32 + (size_t)kt * 128, bDst + i * 4096);
    }
    __syncthreads();
    #pragma unroll
    for (int kk = 0; kk < 2; kk++) {
      f16x8 af[4], bf[4];
      const int rbyte = ((l >> 4) << 4) + kk * 64;
      #pragma unroll
      for (int i = 0; i < 4; i++) {
        const int ra = wm * 64 + i * 16 + (l & 15);
        af[i] = *(const f16x8*)((const char*)Al + ra * 128 + (rbyte ^ ((ra & 7) << 4)));
        const int rb = wn * 64 + i * 16 + (l & 15);
        bf[i] = *(const f16x8*)((const char*)Bl + rb * 128 + (rbyte ^ ((rb & 7) << 4)));
      }
      #pragma unroll
      for (int i = 0; i < 4; i++)
        #pragma unroll
        for (int j = 0; j < 4; j++)
          acc[i][j] = __builtin_amdgcn_mfma_f32_16x16x32_f16(af[i], bf[j], acc[i][j], 0, 0, 0);
    }
  }

  #pragma unroll
  for (int j = 0; j < 4; j++) {
    const int col = n0 + wn * 64 + j * 16 + (l & 15);
    const float s = sc[col], h = sh[col];
    #pragma unroll
    for (int i = 0; i < 4; i++) {
      const int rr = r0 + m0 + wm * 64 + i * 16 + ((l >> 4) << 2);
      #pragma unroll
      for (int rg = 0; rg < 4; rg++) {
        const int r = rr + rg;
        if (r < N_PTS) {
          float v = acc[i][j][rg] * s + h;
          out[(size_t)r * COUT + col] = fmaxf(v, 0.f);
        }
      }
    }
  }
}

extern "C" void kernel_launch(void* const* d_in, const int* in_sizes, int n_in,
                              void* d_out, int out_size, void* d_ws, size_t ws_size,
                              hipStream_t stream) {
  (void)in_sizes; (void)n_in; (void)out_size;
  const float* p   = (const float*)d_in[0];
  const float* x   = (const float*)d_in[1];
  const float* kp  = (const float*)d_in[2];
  const float* w   = (const float*)d_in[3];
  const float* cb  = (const float*)d_in[4];
  const float* g   = (const float*)d_in[5];
  const float* be  = (const float*)d_in[6];
  const float* mu  = (const float*)d_in[7];
  const float* var = (const float*)d_in[8];
  const int* idx   = (const int*)d_in[9];
  float* out = (float*)d_out;

  char* ws = (char*)d_ws;
  size_t off = 0;
  __half* wt  = (__half*)(ws + off); off += (size_t)COUT * KP * 2;   // 1.1 MB
  float*  sc  = (float*)(ws + off);  off += 1024;
  float*  sh  = (float*)(ws + off);  off += 1024;
  __half* xh  = (__half*)(ws + off); off += (size_t)N_PTS * CIN * 2; // 25.6 MB
  __half* agg = (__half*)(ws + off);
  size_t avail = (ws_size > off) ? (ws_size - off) : 0;

  size_t maxrows = avail / ((size_t)KP * 2);
  int rows = CHROWS;                                  // 211 MB chunk (fits 400 MB ws)
  if (maxrows < (size_t)rows) rows = (int)(maxrows & ~(size_t)127);
  if (rows < 128) rows = 128;

  hipLaunchKernelGGL(k_prep_x, dim3(N_PTS * CIN / 1024), dim3(256), 0, stream, x, xh);
  hipLaunchKernelGGL(k_prep_w, dim3(COUT * KP / 256), dim3(256), 0, stream,
                     w, cb, g, be, mu, var, wt, sc, sh);

  for (int row0 = 0; row0 < N_PTS; row0 += rows) {
    int rr = MPAD - row0;
    if (rr > rows) rr = rows;
    hipLaunchKernelGGL(k_agg, dim3(rr / 4), dim3(256), 0, stream, p, xh, kp, idx, agg, row0);
    hipLaunchKernelGGL(k_gemm, dim3(2, rr / 128), dim3(256), 0, stream, agg, wt, sc, sh, out, row0);
  }
}

// Round 9
// 519.040 us; speedup vs baseline: 1.2976x; 1.0729x over previous
//
#include <hip/hip_runtime.h>
#include <hip/hip_fp16.h>

#define N_PTS   100000
#define KNB     16
#define CIN     128
#define COUT    256
#define NKP     15
#define CCH     131
#define KP      2112         // 132 c-slots * 16 m-slots, c-major (m fastest)
#define MPAD    100096       // 782 * 128
#define CHROWS  50048        // 2 chunks; agg buffer 211 MB (ws = 400 MB total)

typedef _Float16 f16x8 __attribute__((ext_vector_type(8)));
typedef float    f32x4 __attribute__((ext_vector_type(4)));
typedef unsigned int u32x2 __attribute__((ext_vector_type(2)));

__device__ __forceinline__ void g2lds16(const void* g, void* l) {
  __builtin_amdgcn_global_load_lds((const __attribute__((address_space(1))) void*)g,
                                   (__attribute__((address_space(3))) void*)l, 16, 0, 0);
}

// ---------------- prep: x -> f16 ----------------
__global__ __launch_bounds__(256) void k_prep_x(const float* __restrict__ x,
                                                __half* __restrict__ xh) {
  int i = blockIdx.x * 256 + threadIdx.x;           // 3.2M threads, 4 elems each
  float4 v = ((const float4*)x)[i];
  __half2* o = (__half2*)xh;
  o[i * 2]     = __floats2half2_rn(v.x, v.y);
  o[i * 2 + 1] = __floats2half2_rn(v.z, v.w);
}

// ---------------- prep: W repack + BN fold ----------------
// c-slot -> channel permutation: c = g*16+j (c<128) maps to x-channel 8j+g;
// c in 128..130 -> pj channel c-128. Reference channel order: [pj(3), x(128)].
__global__ __launch_bounds__(256) void k_prep_w(
    const float* __restrict__ w, const float* __restrict__ cb,
    const float* __restrict__ g, const float* __restrict__ be,
    const float* __restrict__ mu, const float* __restrict__ var,
    __half* __restrict__ wt, float* __restrict__ sc, float* __restrict__ sh) {
  int gid = blockIdx.x * 256 + threadIdx.x;         // COUT*KP threads
  int o = gid / KP, r = gid - o * KP;
  int c = r >> 4, m = r & 15;
  float v = 0.f;
  if (m < 15 && c < 131) {
    int refch = (c < 128) ? (8 * (c & 15) + (c >> 4) + 3) : (c - 128);
    v = w[(o * CCH + refch) * NKP + m];
  }
  wt[gid] = __float2half(v);
  if (gid < COUT) {
    float s = g[gid] / sqrtf(var[gid] + 1e-5f);
    sc[gid] = s;
    sh[gid] = (cb[gid] - mu[gid]) * s + be[gid];
  }
}

// ---------------- agg: direct-gather MFMA aggregation, one wave per point ----------------
__global__ __launch_bounds__(256) void k_agg(
    const float* __restrict__ p, const __half* __restrict__ xh,
    const float* __restrict__ kp, const int* __restrict__ idx,
    __half* __restrict__ agg, int r0) {
  __shared__ float pj[4][16][4];
  __shared__ float co[4][16][16];                   // co[k][m]
  const int l = threadIdx.x & 63;
  const int w = threadIdx.x >> 6;
  const int n = r0 + blockIdx.x * 4 + w;
  const int nc = (n < N_PTS) ? n : (N_PTS - 1);
  const int cfix = l & 15;
  const int nbr = idx[nc * KNB + cfix];

  // neighbor-row byte offsets for this lane's k-set: k = ((l>>4)&1)*8 + i
  int rowoff[8];
  #pragma unroll
  for (int i = 0; i < 8; i++)
    rowoff[i] = __shfl(nbr, ((l >> 4) & 1) * 8 + i) * (CIN * 2);

  // hoisted gather: 8 x 16B per lane; 16 lanes cover 256B contiguous per row.
  const char* xb = (const char*)xh + cfix * 16;
  f16x8 xq[8];
  #pragma unroll
  for (int i = 0; i < 8; i++)
    xq[i] = *(const f16x8*)(xb + (size_t)(unsigned)rowoff[i]);

  // phase 0: relative coords + max-norm (replicated per 16-lane group)
  const float cx = p[nc * 3], cy = p[nc * 3 + 1], cz = p[nc * 3 + 2];
  float ax = p[nbr * 3]     - cx;
  float ay = p[nbr * 3 + 1] - cy;
  float az = p[nbr * 3 + 2] - cz;
  float mx = sqrtf(ax * ax + ay * ay + az * az);
  #pragma unroll
  for (int d = 1; d < 16; d <<= 1) mx = fmaxf(mx, __shfl_xor(mx, d));
  const float inv = 1.0f / (mx + 1e-10f);
  ax *= inv; ay *= inv; az *= inv;

  if (l < 16) { pj[w][l][0] = ax; pj[w][l][1] = ay; pj[w][l][2] = az; pj[w][l][3] = 0.f; }
  __syncthreads();

  // phase 1: corr for k=l>>2, m=(l&3)*4+j  (m==15 -> 0)
  const int k1 = l >> 2;
  f32x4 pv = *(const f32x4*)&pj[w][k1][0];
  f32x4 cc;
  #pragma unroll
  for (int j = 0; j < 4; j++) {
    int m = (l & 3) * 4 + j;
    if (m < 15) {
      float dx = kp[m * 3] - pv[0], dy = kp[m * 3 + 1] - pv[1], dz = kp[m * 3 + 2] - pv[2];
      cc[j] = __expf((dx * dx + dy * dy + dz * dz) * -5.5555553f);
    } else cc[j] = 0.f;
  }
  *(f32x4*)&co[w][k1][(l & 3) * 4] = cc;
  __syncthreads();

  // A-frag: corr[m=l&15][k=(l>>4)*8+i], lanes 0..31; zero elsewhere
  f16x8 af = {};
  if (l < 32) {
    #pragma unroll
    for (int i = 0; i < 8; i++)
      af[i] = (_Float16)co[w][(l >> 4) * 8 + i][l & 15];
  }

  const bool live = (n < N_PTS);
  const int g4 = (l >> 4) * 4;
  char* outp = (char*)(agg + (size_t)(n - r0) * KP) + cfix * 32 + g4 * 2;

  #pragma unroll
  for (int g = 0; g < 8; g++) {
    f16x8 bf;
    #pragma unroll
    for (int i = 0; i < 8; i++)
      bf[i] = xq[i][g];
    f32x4 d = __builtin_amdgcn_mfma_f32_16x16x32_f16(af, bf, (f32x4){0.f, 0.f, 0.f, 0.f}, 0, 0, 0);
    if (live) {
      __half2 h0 = __floats2half2_rn(d[0], d[1]);
      __half2 h1 = __floats2half2_rn(d[2], d[3]);
      u32x2 u; u.x = *(unsigned int*)&h0; u.y = *(unsigned int*)&h1;
      *(u32x2*)(outp + g * 512) = u;
    }
  }
  // group 8: pj channels (c=128..130) + zero col c=131
  {
    f16x8 bf = {};
    if (l < 32 && cfix < 3) {
      #pragma unroll
      for (int i = 0; i < 8; i++)
        bf[i] = (_Float16)pj[w][(l >> 4) * 8 + i][cfix];
    }
    f32x4 d = __builtin_amdgcn_mfma_f32_16x16x32_f16(af, bf, (f32x4){0.f, 0.f, 0.f, 0.f}, 0, 0, 0);
    if (live && cfix < 4) {
      __half2 h0 = __floats2half2_rn(d[0], d[1]);
      __half2 h1 = __floats2half2_rn(d[2], d[3]);
      u32x2 u; u.x = *(unsigned int*)&h0; u.y = *(unsigned int*)&h1;
      *(u32x2*)(outp + 8 * 512) = u;
    }
  }
}

// ---------------- GEMM: 2-phase dbuf, counted vmcnt (loads in flight across barrier) ----
__global__ __launch_bounds__(256) void k_gemm(
    const __half* __restrict__ A, const __half* __restrict__ B,
    const float* __restrict__ sc, const float* __restrict__ sh,
    float* __restrict__ out, int r0) {
  __shared__ __align__(16) __half Al[2][128 * 64];  // 2 x 16 KB
  __shared__ __align__(16) __half Bl[2][128 * 64];  // 2 x 16 KB
  const int t = threadIdx.x;
  const int l = t & 63;
  const int bn = blockIdx.x, bm = blockIdx.y;
  const int m0 = bm * 128, n0 = bn * 128;
  const int w = t >> 6;
  const int wm = w >> 1, wn = w & 1;

  f32x4 acc[4][4] = {};

  const int arow = t >> 3;
  const int kb   = (t & 7) << 4;
  const int kbsw = kb ^ ((arow & 7) << 4);          // pre-swizzled source (T2, rule 21)
  const char* aSrc = (const char*)(A + (size_t)(m0 + arow) * KP) + kbsw;
  const char* bSrc = (const char*)(B + (size_t)(n0 + arow) * KP) + kbsw;
  const size_t rowStride32 = (size_t)32 * KP * 2;

  #define STAGE(BUF, KT) { _Pragma("unroll") for (int i = 0; i < 4; i++) {            \
      g2lds16(aSrc + i * rowStride32 + (size_t)(KT) * 128,                            \
              (char*)Al + (BUF) * 16384 + t * 16 + i * 4096);                         \
      g2lds16(bSrc + i * rowStride32 + (size_t)(KT) * 128,                            \
              (char*)Bl + (BUF) * 16384 + t * 16 + i * 4096); } }

  const int NT = KP / 64;                           // 33
  STAGE(0, 0)
  __builtin_amdgcn_sched_barrier(0);

  for (int kt = 0; kt < NT; kt++) {
    const int cur = kt & 1;
    if (kt + 1 < NT) {
      STAGE(cur ^ 1, kt + 1)                        // issue next tile: stays in flight
      __builtin_amdgcn_sched_barrier(0);
      asm volatile("s_waitcnt vmcnt(8)" ::: "memory");   // STAGE(kt) landed; 8 remain
    } else {
      asm volatile("s_waitcnt vmcnt(0)" ::: "memory");
    }
    __builtin_amdgcn_s_barrier();                   // tile kt visible to all waves
    __builtin_amdgcn_sched_barrier(0);

    const char* Ab = (const char*)Al + cur * 16384;
    const char* Bb = (const char*)Bl + cur * 16384;
    #pragma unroll
    for (int kk = 0; kk < 2; kk++) {
      f16x8 af[4], bf[4];
      const int rbyte = ((l >> 4) << 4) + kk * 64;
      #pragma unroll
      for (int i = 0; i < 4; i++) {
        const int ra = wm * 64 + i * 16 + (l & 15);
        af[i] = *(const f16x8*)(Ab + ra * 128 + (rbyte ^ ((ra & 7) << 4)));
        const int rb = wn * 64 + i * 16 + (l & 15);
        bf[i] = *(const f16x8*)(Bb + rb * 128 + (rbyte ^ ((rb & 7) << 4)));
      }
      #pragma unroll
      for (int i = 0; i < 4; i++)
        #pragma unroll
        for (int j = 0; j < 4; j++)
          acc[i][j] = __builtin_amdgcn_mfma_f32_16x16x32_f16(af[i], bf[j], acc[i][j], 0, 0, 0);
    }

    asm volatile("s_waitcnt lgkmcnt(0)" ::: "memory");   // our reads of buf cur done
    __builtin_amdgcn_s_barrier();                   // all waves done -> cur may be overwritten
    __builtin_amdgcn_sched_barrier(0);
  }
  #undef STAGE

  #pragma unroll
  for (int j = 0; j < 4; j++) {
    const int col = n0 + wn * 64 + j * 16 + (l & 15);
    const float s = sc[col], h = sh[col];
    #pragma unroll
    for (int i = 0; i < 4; i++) {
      const int rr = r0 + m0 + wm * 64 + i * 16 + ((l >> 4) << 2);
      #pragma unroll
      for (int rg = 0; rg < 4; rg++) {
        const int r = rr + rg;
        if (r < N_PTS) {
          float v = acc[i][j][rg] * s + h;
          out[(size_t)r * COUT + col] = fmaxf(v, 0.f);
        }
      }
    }
  }
}

extern "C" void kernel_launch(void* const* d_in, const int* in_sizes, int n_in,
                              void* d_out, int out_size, void* d_ws, size_t ws_size,
                              hipStream_t stream) {
  (void)in_sizes; (void)n_in; (void)out_size;
  const float* p   = (const float*)d_in[0];
  const float* x   = (const float*)d_in[1];
  const float* kp  = (const float*)d_in[2];
  const float* w   = (const float*)d_in[3];
  const float* cb  = (const float*)d_in[4];
  const float* g   = (const float*)d_in[5];
  const float* be  = (const float*)d_in[6];
  const float* mu  = (const float*)d_in[7];
  const float* var = (const float*)d_in[8];
  const int* idx   = (const int*)d_in[9];
  float* out = (float*)d_out;

  char* ws = (char*)d_ws;
  size_t off = 0;
  __half* wt  = (__half*)(ws + off); off += (size_t)COUT * KP * 2;   // 1.1 MB
  float*  sc  = (float*)(ws + off);  off += 1024;
  float*  sh  = (float*)(ws + off);  off += 1024;
  __half* xh  = (__half*)(ws + off); off += (size_t)N_PTS * CIN * 2; // 25.6 MB
  __half* agg = (__half*)(ws + off);
  size_t avail = (ws_size > off) ? (ws_size - off) : 0;

  size_t maxrows = avail / ((size_t)KP * 2);
  int rows = CHROWS;                                  // 211 MB chunk (fits 400 MB ws)
  if (maxrows < (size_t)rows) rows = (int)(maxrows & ~(size_t)127);
  if (rows < 128) rows = 128;

  hipLaunchKernelGGL(k_prep_x, dim3(N_PTS * CIN / 1024), dim3(256), 0, stream, x, xh);
  hipLaunchKernelGGL(k_prep_w, dim3(COUT * KP / 256), dim3(256), 0, stream,
                     w, cb, g, be, mu, var, wt, sc, sh);

  for (int row0 = 0; row0 < N_PTS; row0 += rows) {
    int rr = MPAD - row0;
    if (rr > rows) rr = rows;
    hipLaunchKernelGGL(k_agg, dim3(rr / 4), dim3(256), 0, stream, p, xh, kp, idx, agg, row0);
    hipLaunchKernelGGL(k_gemm, dim3(2, rr / 128), dim3(256), 0, stream, agg, wt, sc, sh, out, row0);
  }
}

// Round 10
// 506.304 us; speedup vs baseline: 1.3303x; 1.0252x over previous
//
#include <hip/hip_runtime.h>
#include <hip/hip_fp16.h>

#define N_PTS   100000
#define KNB     16
#define CIN     128
#define COUT    256
#define NKP     15
#define CCH     131
#define KP      2112         // 132 c-slots * 16 m-slots, c-major (m fastest)
#define MPAD    100096       // 782 * 128
#define CHROWS  50048        // 2 chunks; agg buffer 211 MB (ws = 400 MB total)

typedef _Float16 f16x8 __attribute__((ext_vector_type(8)));
typedef float    f32x4 __attribute__((ext_vector_type(4)));
typedef unsigned int u32x2 __attribute__((ext_vector_type(2)));

__device__ __forceinline__ void g2lds16(const void* g, void* l) {
  __builtin_amdgcn_global_load_lds((const __attribute__((address_space(1))) void*)g,
                                   (__attribute__((address_space(3))) void*)l, 16, 0, 0);
}

// ---------------- prep: x -> f16 ----------------
__global__ __launch_bounds__(256) void k_prep_x(const float* __restrict__ x,
                                                __half* __restrict__ xh) {
  int i = blockIdx.x * 256 + threadIdx.x;           // 3.2M threads, 4 elems each
  float4 v = ((const float4*)x)[i];
  __half2* o = (__half2*)xh;
  o[i * 2]     = __floats2half2_rn(v.x, v.y);
  o[i * 2 + 1] = __floats2half2_rn(v.z, v.w);
}

// ---------------- prep: W repack + BN fold ----------------
// c-slot -> channel permutation: c = g*16+j (c<128) maps to x-channel 8j+g;
// c in 128..130 -> pj channel c-128. Reference channel order: [pj(3), x(128)].
__global__ __launch_bounds__(256) void k_prep_w(
    const float* __restrict__ w, const float* __restrict__ cb,
    const float* __restrict__ g, const float* __restrict__ be,
    const float* __restrict__ mu, const float* __restrict__ var,
    __half* __restrict__ wt, float* __restrict__ sc, float* __restrict__ sh) {
  int gid = blockIdx.x * 256 + threadIdx.x;         // COUT*KP threads
  int o = gid / KP, r = gid - o * KP;
  int c = r >> 4, m = r & 15;
  float v = 0.f;
  if (m < 15 && c < 131) {
    int refch = (c < 128) ? (8 * (c & 15) + (c >> 4) + 3) : (c - 128);
    v = w[(o * CCH + refch) * NKP + m];
  }
  wt[gid] = __float2half(v);
  if (gid < COUT) {
    float s = g[gid] / sqrtf(var[gid] + 1e-5f);
    sc[gid] = s;
    sh[gid] = (cb[gid] - mu[gid]) * s + be[gid];
  }
}

// ---------------- agg: direct-gather MFMA aggregation, one wave per point ----------------
__global__ __launch_bounds__(256) void k_agg(
    const float* __restrict__ p, const __half* __restrict__ xh,
    const float* __restrict__ kp, const int* __restrict__ idx,
    __half* __restrict__ agg, int r0) {
  __shared__ float pj[4][16][4];
  __shared__ float co[4][16][16];                   // co[k][m]
  const int l = threadIdx.x & 63;
  const int w = threadIdx.x >> 6;
  const int n = r0 + blockIdx.x * 4 + w;
  const int nc = (n < N_PTS) ? n : (N_PTS - 1);
  const int cfix = l & 15;
  const int nbr = idx[nc * KNB + cfix];

  // neighbor-row byte offsets for this lane's k-set: k = ((l>>4)&1)*8 + i
  int rowoff[8];
  #pragma unroll
  for (int i = 0; i < 8; i++)
    rowoff[i] = __shfl(nbr, ((l >> 4) & 1) * 8 + i) * (CIN * 2);

  // hoisted gather: 8 x 16B per lane; 16 lanes cover 256B contiguous per row.
  const char* xb = (const char*)xh + cfix * 16;
  f16x8 xq[8];
  #pragma unroll
  for (int i = 0; i < 8; i++)
    xq[i] = *(const f16x8*)(xb + (size_t)(unsigned)rowoff[i]);

  // phase 0: relative coords + max-norm (replicated per 16-lane group)
  const float cx = p[nc * 3], cy = p[nc * 3 + 1], cz = p[nc * 3 + 2];
  float ax = p[nbr * 3]     - cx;
  float ay = p[nbr * 3 + 1] - cy;
  float az = p[nbr * 3 + 2] - cz;
  float mx = sqrtf(ax * ax + ay * ay + az * az);
  #pragma unroll
  for (int d = 1; d < 16; d <<= 1) mx = fmaxf(mx, __shfl_xor(mx, d));
  const float inv = 1.0f / (mx + 1e-10f);
  ax *= inv; ay *= inv; az *= inv;

  if (l < 16) { pj[w][l][0] = ax; pj[w][l][1] = ay; pj[w][l][2] = az; pj[w][l][3] = 0.f; }
  __syncthreads();

  // phase 1: corr for k=l>>2, m=(l&3)*4+j  (m==15 -> 0)
  const int k1 = l >> 2;
  f32x4 pv = *(const f32x4*)&pj[w][k1][0];
  f32x4 cc;
  #pragma unroll
  for (int j = 0; j < 4; j++) {
    int m = (l & 3) * 4 + j;
    if (m < 15) {
      float dx = kp[m * 3] - pv[0], dy = kp[m * 3 + 1] - pv[1], dz = kp[m * 3 + 2] - pv[2];
      cc[j] = __expf((dx * dx + dy * dy + dz * dz) * -5.5555553f);
    } else cc[j] = 0.f;
  }
  *(f32x4*)&co[w][k1][(l & 3) * 4] = cc;
  __syncthreads();

  // A-frag: corr[m=l&15][k=(l>>4)*8+i], lanes 0..31; zero elsewhere
  f16x8 af = {};
  if (l < 32) {
    #pragma unroll
    for (int i = 0; i < 8; i++)
      af[i] = (_Float16)co[w][(l >> 4) * 8 + i][l & 15];
  }

  const bool live = (n < N_PTS);
  const int g4 = (l >> 4) * 4;
  char* outp = (char*)(agg + (size_t)(n - r0) * KP) + cfix * 32 + g4 * 2;

  #pragma unroll
  for (int g = 0; g < 8; g++) {
    f16x8 bf;
    #pragma unroll
    for (int i = 0; i < 8; i++)
      bf[i] = xq[i][g];
    f32x4 d = __builtin_amdgcn_mfma_f32_16x16x32_f16(af, bf, (f32x4){0.f, 0.f, 0.f, 0.f}, 0, 0, 0);
    if (live) {
      __half2 h0 = __floats2half2_rn(d[0], d[1]);
      __half2 h1 = __floats2half2_rn(d[2], d[3]);
      u32x2 u; u.x = *(unsigned int*)&h0; u.y = *(unsigned int*)&h1;
      *(u32x2*)(outp + g * 512) = u;
    }
  }
  // group 8: pj channels (c=128..130) + zero col c=131
  {
    f16x8 bf = {};
    if (l < 32 && cfix < 3) {
      #pragma unroll
      for (int i = 0; i < 8; i++)
        bf[i] = (_Float16)pj[w][(l >> 4) * 8 + i][cfix];
    }
    f32x4 d = __builtin_amdgcn_mfma_f32_16x16x32_f16(af, bf, (f32x4){0.f, 0.f, 0.f, 0.f}, 0, 0, 0);
    if (live && cfix < 4) {
      __half2 h0 = __floats2half2_rn(d[0], d[1]);
      __half2 h1 = __floats2half2_rn(d[2], d[3]);
      u32x2 u; u.x = *(unsigned int*)&h0; u.y = *(unsigned int*)&h1;
      *(u32x2*)(outp + 8 * 512) = u;
    }
  }
}

// ---------------- GEMM: BM=64 BN=128 BK=64, 2-deep dbuf, counted vmcnt ----------------
// 3 blocks/CU (48 KB LDS), grid (2, rows/64) = 1564 blocks -> block-level TLP
__global__ __launch_bounds__(256) void k_gemm(
    const __half* __restrict__ A, const __half* __restrict__ B,
    const float* __restrict__ sc, const float* __restrict__ sh,
    float* __restrict__ out, int r0) {
  __shared__ __align__(16) __half Al[2][64 * 64];   // 2 x 8 KB
  __shared__ __align__(16) __half Bl[2][128 * 64];  // 2 x 16 KB
  const int t = threadIdx.x;
  const int l = t & 63;
  const int bn = blockIdx.x, bm = blockIdx.y;
  const int m0 = bm * 64, n0 = bn * 128;
  const int w = t >> 6;
  const int wm = w >> 1, wn = w & 1;                // wave tile: rows wm*32, cols wn*64

  f32x4 acc[2][4] = {};

  const int arow = t >> 3;                          // 0..31
  const int kb   = (t & 7) << 4;
  const int kbsw = kb ^ ((arow & 7) << 4);          // pre-swizzled source (T2, rule 21)
  const char* aSrc = (const char*)(A + (size_t)(m0 + arow) * KP) + kbsw;
  const char* bSrc = (const char*)(B + (size_t)(n0 + arow) * KP) + kbsw;
  const size_t rowStride32 = (size_t)32 * KP * 2;

  // per K-step: A rows arow,arow+32 (2 loads); B rows arow+{0,32,64,96} (4 loads)
  #define STAGE(BUF, KT) {                                                            \
      g2lds16(aSrc + (size_t)(KT) * 128,                                              \
              (char*)Al + (BUF) * 8192 + t * 16);                                     \
      g2lds16(aSrc + rowStride32 + (size_t)(KT) * 128,                                \
              (char*)Al + (BUF) * 8192 + t * 16 + 4096);                              \
      _Pragma("unroll") for (int i = 0; i < 4; i++)                                   \
        g2lds16(bSrc + i * rowStride32 + (size_t)(KT) * 128,                          \
                (char*)Bl + (BUF) * 16384 + t * 16 + i * 4096); }

  const int NT = KP / 64;                           // 33
  STAGE(0, 0)
  __builtin_amdgcn_sched_barrier(0);

  for (int kt = 0; kt < NT; kt++) {
    const int cur = kt & 1;
    if (kt + 1 < NT) {
      STAGE(cur ^ 1, kt + 1)                        // 6 loads stay in flight
      __builtin_amdgcn_sched_barrier(0);
      asm volatile("s_waitcnt vmcnt(6)" ::: "memory");   // STAGE(kt)'s 6 landed
    } else {
      asm volatile("s_waitcnt vmcnt(0)" ::: "memory");
    }
    __builtin_amdgcn_s_barrier();                   // tile kt visible to all waves
    __builtin_amdgcn_sched_barrier(0);

    const char* Ab = (const char*)Al + cur * 8192;
    const char* Bb = (const char*)Bl + cur * 16384;
    #pragma unroll
    for (int kk = 0; kk < 2; kk++) {
      f16x8 af[2], bf[4];
      const int rbyte = ((l >> 4) << 4) + kk * 64;
      #pragma unroll
      for (int i = 0; i < 2; i++) {
        const int ra = wm * 32 + i * 16 + (l & 15);
        af[i] = *(const f16x8*)(Ab + ra * 128 + (rbyte ^ ((ra & 7) << 4)));
      }
      #pragma unroll
      for (int j = 0; j < 4; j++) {
        const int rb = wn * 64 + j * 16 + (l & 15);
        bf[j] = *(const f16x8*)(Bb + rb * 128 + (rbyte ^ ((rb & 7) << 4)));
      }
      #pragma unroll
      for (int i = 0; i < 2; i++)
        #pragma unroll
        for (int j = 0; j < 4; j++)
          acc[i][j] = __builtin_amdgcn_mfma_f32_16x16x32_f16(af[i], bf[j], acc[i][j], 0, 0, 0);
    }

    asm volatile("s_waitcnt lgkmcnt(0)" ::: "memory");   // our reads of buf cur done
    __builtin_amdgcn_s_barrier();                   // all waves done -> cur may be overwritten
    __builtin_amdgcn_sched_barrier(0);
  }
  #undef STAGE

  #pragma unroll
  for (int j = 0; j < 4; j++) {
    const int col = n0 + wn * 64 + j * 16 + (l & 15);
    const float s = sc[col], h = sh[col];
    #pragma unroll
    for (int i = 0; i < 2; i++) {
      const int rr = r0 + m0 + wm * 32 + i * 16 + ((l >> 4) << 2);
      #pragma unroll
      for (int rg = 0; rg < 4; rg++) {
        const int r = rr + rg;
        if (r < N_PTS) {
          float v = acc[i][j][rg] * s + h;
          out[(size_t)r * COUT + col] = fmaxf(v, 0.f);
        }
      }
    }
  }
}

extern "C" void kernel_launch(void* const* d_in, const int* in_sizes, int n_in,
                              void* d_out, int out_size, void* d_ws, size_t ws_size,
                              hipStream_t stream) {
  (void)in_sizes; (void)n_in; (void)out_size;
  const float* p   = (const float*)d_in[0];
  const float* x   = (const float*)d_in[1];
  const float* kp  = (const float*)d_in[2];
  const float* w   = (const float*)d_in[3];
  const float* cb  = (const float*)d_in[4];
  const float* g   = (const float*)d_in[5];
  const float* be  = (const float*)d_in[6];
  const float* mu  = (const float*)d_in[7];
  const float* var = (const float*)d_in[8];
  const int* idx   = (const int*)d_in[9];
  float* out = (float*)d_out;

  char* ws = (char*)d_ws;
  size_t off = 0;
  __half* wt  = (__half*)(ws + off); off += (size_t)COUT * KP * 2;   // 1.1 MB
  float*  sc  = (float*)(ws + off);  off += 1024;
  float*  sh  = (float*)(ws + off);  off += 1024;
  __half* xh  = (__half*)(ws + off); off += (size_t)N_PTS * CIN * 2; // 25.6 MB
  __half* agg = (__half*)(ws + off);
  size_t avail = (ws_size > off) ? (ws_size - off) : 0;

  size_t maxrows = avail / ((size_t)KP * 2);
  int rows = CHROWS;                                  // 211 MB chunk (fits 400 MB ws)
  if (maxrows < (size_t)rows) rows = (int)(maxrows & ~(size_t)127);
  if (rows < 128) rows = 128;

  hipLaunchKernelGGL(k_prep_x, dim3(N_PTS * CIN / 1024), dim3(256), 0, stream, x, xh);
  hipLaunchKernelGGL(k_prep_w, dim3(COUT * KP / 256), dim3(256), 0, stream,
                     w, cb, g, be, mu, var, wt, sc, sh);

  for (int row0 = 0; row0 < N_PTS; row0 += rows) {
    int rr = MPAD - row0;
    if (rr > rows) rr = rows;
    hipLaunchKernelGGL(k_agg, dim3(rr / 4), dim3(256), 0, stream, p, xh, kp, idx, agg, row0);
    hipLaunchKernelGGL(k_gemm, dim3(2, rr / 64), dim3(256), 0, stream, agg, wt, sc, sh, out, row0);
  }
}